// Round 4
// baseline (494.985 us; speedup 1.0000x reference)
//
#include <hip/hip_runtime.h>
#include <hip/hip_bf16.h>
#include <float.h>

#define F 128          // hidden = H*C
#define HEADS 4
#define CPH 32

// ---------------- CSR build ----------------

__global__ void count_deg_kernel(const int* __restrict__ dst, int* __restrict__ deg, int E) {
    int i = blockIdx.x * blockDim.x + threadIdx.x;
    if (i < E) atomicAdd(&deg[dst[i]], 1);
}

__global__ __launch_bounds__(1024) void scan1_kernel(const int* __restrict__ deg,
                                                     int* __restrict__ excl,
                                                     int* __restrict__ bsums, int n) {
    __shared__ int tmp[1024];
    int i = blockIdx.x * 1024 + threadIdx.x;
    int v = (i < n) ? deg[i] : 0;
    tmp[threadIdx.x] = v;
    __syncthreads();
    for (int o = 1; o < 1024; o <<= 1) {
        int a = (threadIdx.x >= o) ? tmp[threadIdx.x - o] : 0;
        __syncthreads();
        tmp[threadIdx.x] += a;
        __syncthreads();
    }
    if (i < n) excl[i] = tmp[threadIdx.x] - v;
    if (threadIdx.x == 1023) bsums[blockIdx.x] = tmp[1023];
}

__global__ __launch_bounds__(1024) void scan2_kernel(int* __restrict__ bsums, int nb) {
    __shared__ int tmp[1024];
    int v = (threadIdx.x < nb) ? bsums[threadIdx.x] : 0;
    tmp[threadIdx.x] = v;
    __syncthreads();
    for (int o = 1; o < 1024; o <<= 1) {
        int a = (threadIdx.x >= o) ? tmp[threadIdx.x - o] : 0;
        __syncthreads();
        tmp[threadIdx.x] += a;
        __syncthreads();
    }
    if (threadIdx.x < nb) bsums[threadIdx.x] = tmp[threadIdx.x] - v;  // exclusive
}

// writes row_ptr and also initializes cursor = row start (scatter bumps it directly)
__global__ void scan3_kernel(const int* __restrict__ excl, const int* __restrict__ bsums,
                             int* __restrict__ row_ptr, int* __restrict__ cursor,
                             int n, int E) {
    int i = blockIdx.x * 256 + threadIdx.x;
    if (i < n) {
        int v = excl[i] + bsums[i >> 10];
        row_ptr[i] = v;
        cursor[i] = v;
    }
    if (i == n) row_ptr[n] = E;
}

__global__ void scatter_kernel(const int* __restrict__ src, const int* __restrict__ dst,
                               int* __restrict__ cursor, int* __restrict__ srcs, int E) {
    int i = blockIdx.x * blockDim.x + threadIdx.x;
    if (i < E) {
        int pos = atomicAdd(&cursor[dst[i]], 1);
        srcs[pos] = src[i];
    }
}

// ---------------- dual fp32 GEMM, LDS-free: Y1 = X@W1+b1, Y2 = X@W2+b2 ----------------
// W stays in L2 (128KB total, read per-thread as float4: thread owns cols 4cl..4cl+3).
// 256 thr/block, 64 rows/block, 8 rows/thread. No LDS, no syncthreads -> occupancy
// bounded by VGPR only. X row-chunks are wave-broadcast float4 loads (L1-served).

__global__ __launch_bounds__(256) void dual_gemm128_kernel(
    const float4* __restrict__ X4,
    const float4* __restrict__ W14, const float4* __restrict__ b14,
    const float4* __restrict__ W24, const float4* __restrict__ b24,
    float4* __restrict__ Y14, float4* __restrict__ Y24, int N)
{
    int cl  = threadIdx.x & 31;        // col-quad: output cols 4cl..4cl+3
    int grp = threadIdx.x >> 5;        // 0..7
    int row0 = blockIdx.x * 64 + grp * 8;

    float4 a1[8], a2[8];
    #pragma unroll
    for (int i = 0; i < 8; ++i) {
        a1[i] = make_float4(0.f, 0.f, 0.f, 0.f);
        a2[i] = make_float4(0.f, 0.f, 0.f, 0.f);
    }

    // clamp row indices for loads (guard stores later) to keep full-wave code
    int r[8];
    #pragma unroll
    for (int i = 0; i < 8; ++i) {
        int rr = row0 + i;
        r[i] = rr < N ? rr : N - 1;
    }

    #pragma unroll 2
    for (int kc = 0; kc < 32; ++kc) {          // k-chunk of 4
        float4 xv[8];
        #pragma unroll
        for (int i = 0; i < 8; ++i)
            xv[i] = X4[(size_t)r[i] * 32 + kc];
        #pragma unroll
        for (int kk = 0; kk < 4; ++kk) {
            float4 w1 = W14[(size_t)(4 * kc + kk) * 32 + cl];
            float4 w2 = W24[(size_t)(4 * kc + kk) * 32 + cl];
            #pragma unroll
            for (int i = 0; i < 8; ++i) {
                float xs = ((const float*)&xv[i])[kk];
                a1[i].x = fmaf(xs, w1.x, a1[i].x);
                a1[i].y = fmaf(xs, w1.y, a1[i].y);
                a1[i].z = fmaf(xs, w1.z, a1[i].z);
                a1[i].w = fmaf(xs, w1.w, a1[i].w);
                a2[i].x = fmaf(xs, w2.x, a2[i].x);
                a2[i].y = fmaf(xs, w2.y, a2[i].y);
                a2[i].z = fmaf(xs, w2.z, a2[i].z);
                a2[i].w = fmaf(xs, w2.w, a2[i].w);
            }
        }
    }

    float4 bi1 = b14[cl];
    float4 bi2 = b24[cl];
    #pragma unroll
    for (int i = 0; i < 8; ++i) {
        if (row0 + i < N) {
            float4 o1, o2;
            o1.x = a1[i].x + bi1.x; o1.y = a1[i].y + bi1.y;
            o1.z = a1[i].z + bi1.z; o1.w = a1[i].w + bi1.w;
            o2.x = a2[i].x + bi2.x; o2.y = a2[i].y + bi2.y;
            o2.z = a2[i].z + bi2.z; o2.w = a2[i].w + bi2.w;
            Y14[(size_t)(row0 + i) * 32 + cl] = o1;
            Y24[(size_t)(row0 + i) * 32 + cl] = o2;
        }
    }
}

// ---------------- fused edge phase (R2 structure, unroll-8) ----------------
// 1 wave per node; thread t owns channels (2t, 2t+1); head group = 16 lanes.
// Plain exp (logits O(5), exp-safe in fp32, math-identical to max-subtracted form).
// 8 independent gather->dot->shfl chains in flight per iteration.

__device__ __forceinline__ float edge_logit(float2 v, float2 xr_t, float2 a_t) {
    float e0 = v.x + xr_t.x; e0 = e0 >= 0.f ? e0 : 0.2f * e0;
    float e1 = v.y + xr_t.y; e1 = e1 >= 0.f ? e1 : 0.2f * e1;
    float p = e0 * a_t.x + e1 * a_t.y;
    p += __shfl_xor(p, 8);   // reduce over 16-lane head group
    p += __shfl_xor(p, 4);
    p += __shfl_xor(p, 2);
    p += __shfl_xor(p, 1);
    return p;
}

__global__ __launch_bounds__(256) void gat_edge_kernel(
    const float2* __restrict__ xl2, const float2* __restrict__ xr2,
    const int* __restrict__ srcs, const int* __restrict__ row_ptr,
    const float2* __restrict__ att2, const float2* __restrict__ bias2,
    float2* __restrict__ out2, int N, int do_relu)
{
    int node = blockIdx.x * 4 + threadIdx.y;
    int t = threadIdx.x;                       // 0..63
    if (node >= N) return;
    float2 xr_t = xr2[(size_t)node * 64 + t];
    float2 a_t  = att2[t];
    int beg = row_ptr[node], end = row_ptr[node + 1];
    float s = 0.f;
    float ox = 0.f, oy = 0.f;
    int i = beg;
    for (; i + 8 <= end; i += 8) {
        int sn0 = srcs[i],     sn1 = srcs[i + 1], sn2 = srcs[i + 2], sn3 = srcs[i + 3];
        int sn4 = srcs[i + 4], sn5 = srcs[i + 5], sn6 = srcs[i + 6], sn7 = srcs[i + 7];
        float2 v0 = xl2[(size_t)sn0 * 64 + t];
        float2 v1 = xl2[(size_t)sn1 * 64 + t];
        float2 v2 = xl2[(size_t)sn2 * 64 + t];
        float2 v3 = xl2[(size_t)sn3 * 64 + t];
        float2 v4 = xl2[(size_t)sn4 * 64 + t];
        float2 v5 = xl2[(size_t)sn5 * 64 + t];
        float2 v6 = xl2[(size_t)sn6 * 64 + t];
        float2 v7 = xl2[(size_t)sn7 * 64 + t];
        float p0 = edge_logit(v0, xr_t, a_t);
        float p1 = edge_logit(v1, xr_t, a_t);
        float p2 = edge_logit(v2, xr_t, a_t);
        float p3 = edge_logit(v3, xr_t, a_t);
        float p4 = edge_logit(v4, xr_t, a_t);
        float p5 = edge_logit(v5, xr_t, a_t);
        float p6 = edge_logit(v6, xr_t, a_t);
        float p7 = edge_logit(v7, xr_t, a_t);
        float w0 = __expf(p0), w1 = __expf(p1), w2 = __expf(p2), w3 = __expf(p3);
        float w4 = __expf(p4), w5 = __expf(p5), w6 = __expf(p6), w7 = __expf(p7);
        s += ((w0 + w1) + (w2 + w3)) + ((w4 + w5) + (w6 + w7));
        ox = fmaf(w0, v0.x, ox); oy = fmaf(w0, v0.y, oy);
        ox = fmaf(w1, v1.x, ox); oy = fmaf(w1, v1.y, oy);
        ox = fmaf(w2, v2.x, ox); oy = fmaf(w2, v2.y, oy);
        ox = fmaf(w3, v3.x, ox); oy = fmaf(w3, v3.y, oy);
        ox = fmaf(w4, v4.x, ox); oy = fmaf(w4, v4.y, oy);
        ox = fmaf(w5, v5.x, ox); oy = fmaf(w5, v5.y, oy);
        ox = fmaf(w6, v6.x, ox); oy = fmaf(w6, v6.y, oy);
        ox = fmaf(w7, v7.x, ox); oy = fmaf(w7, v7.y, oy);
    }
    for (; i + 4 <= end; i += 4) {
        int sn0 = srcs[i], sn1 = srcs[i + 1], sn2 = srcs[i + 2], sn3 = srcs[i + 3];
        float2 v0 = xl2[(size_t)sn0 * 64 + t];
        float2 v1 = xl2[(size_t)sn1 * 64 + t];
        float2 v2 = xl2[(size_t)sn2 * 64 + t];
        float2 v3 = xl2[(size_t)sn3 * 64 + t];
        float p0 = edge_logit(v0, xr_t, a_t);
        float p1 = edge_logit(v1, xr_t, a_t);
        float p2 = edge_logit(v2, xr_t, a_t);
        float p3 = edge_logit(v3, xr_t, a_t);
        float w0 = __expf(p0), w1 = __expf(p1), w2 = __expf(p2), w3 = __expf(p3);
        s += (w0 + w1) + (w2 + w3);
        ox = fmaf(w0, v0.x, ox); oy = fmaf(w0, v0.y, oy);
        ox = fmaf(w1, v1.x, ox); oy = fmaf(w1, v1.y, oy);
        ox = fmaf(w2, v2.x, ox); oy = fmaf(w2, v2.y, oy);
        ox = fmaf(w3, v3.x, ox); oy = fmaf(w3, v3.y, oy);
    }
    for (; i < end; ++i) {
        int sn = srcs[i];
        float2 v = xl2[(size_t)sn * 64 + t];
        float p = edge_logit(v, xr_t, a_t);
        float w = __expf(p);
        s += w;
        ox = fmaf(w, v.x, ox); oy = fmaf(w, v.y, oy);
    }
    float inv = 1.f / (s + 1e-16f);
    float2 bi = bias2[t];
    float rx = ox * inv + bi.x;
    float ry = oy * inv + bi.y;
    if (do_relu) { rx = fmaxf(rx, 0.f); ry = fmaxf(ry, 0.f); }
    float2 rr; rr.x = rx; rr.y = ry;
    out2[(size_t)node * 64 + t] = rr;
}

// ---------------- launch ----------------

extern "C" void kernel_launch(void* const* d_in, const int* in_sizes, int n_in,
                              void* d_out, int out_size, void* d_ws, size_t ws_size,
                              hipStream_t stream)
{
    const float* x    = (const float*)d_in[0];
    const int*   ei   = (const int*)d_in[1];
    const float* Wl1  = (const float*)d_in[2];
    const float* Wr1  = (const float*)d_in[3];
    const float* Wl2  = (const float*)d_in[4];
    const float* Wr2  = (const float*)d_in[5];
    const float* bl1  = (const float*)d_in[6];
    const float* br1  = (const float*)d_in[7];
    const float* bl2  = (const float*)d_in[8];
    const float* br2  = (const float*)d_in[9];
    const float* att1 = (const float*)d_in[10];
    const float* att2 = (const float*)d_in[11];
    const float* b1   = (const float*)d_in[12];
    const float* b2   = (const float*)d_in[13];

    const int N = in_sizes[0] / F;
    const int E = in_sizes[1] / 2;
    const int* src = ei;
    const int* dst = ei + E;

    char* ws = (char*)d_ws;
    size_t off = 0;
    auto alloc = [&](size_t bytes) -> void* {
        void* p = ws + off;
        off = (off + bytes + 255) & ~(size_t)255;
        return p;
    };
    float* xl      = (float*)alloc((size_t)N * F * sizeof(float));
    float* xr      = (float*)alloc((size_t)N * F * sizeof(float));
    float* h       = (float*)alloc((size_t)N * F * sizeof(float));
    int*   row_ptr = (int*)alloc((size_t)(N + 1) * sizeof(int));
    int*   deg     = (int*)alloc((size_t)N * sizeof(int));
    int*   excl    = (int*)alloc((size_t)N * sizeof(int));
    int*   bsums   = (int*)alloc((size_t)1024 * sizeof(int));
    int*   cursor  = (int*)alloc((size_t)N * sizeof(int));
    int*   srcs    = (int*)alloc((size_t)E * sizeof(int));

    // CSR build (edge structure shared by both layers)
    hipMemsetAsync(deg, 0, (size_t)N * sizeof(int), stream);
    count_deg_kernel<<<(E + 255) / 256, 256, 0, stream>>>(dst, deg, E);
    const int nchunks = (N + 1023) / 1024;
    scan1_kernel<<<nchunks, 1024, 0, stream>>>(deg, excl, bsums, N);
    scan2_kernel<<<1, 1024, 0, stream>>>(bsums, nchunks);
    scan3_kernel<<<(N + 256) / 256, 256, 0, stream>>>(excl, bsums, row_ptr, cursor, N, E);
    scatter_kernel<<<(E + 255) / 256, 256, 0, stream>>>(src, dst, cursor, srcs, E);

    const int dual_blocks = (N + 63) / 64;
    dim3 eb(64, 4);
    const int edge_blocks = (N + 3) / 4;

    // layer 1
    dual_gemm128_kernel<<<dual_blocks, 256, 0, stream>>>(
        (const float4*)x, (const float4*)Wl1, (const float4*)bl1,
        (const float4*)Wr1, (const float4*)br1, (float4*)xl, (float4*)xr, N);
    gat_edge_kernel<<<edge_blocks, eb, 0, stream>>>((const float2*)xl, (const float2*)xr,
                                                    srcs, row_ptr, (const float2*)att1,
                                                    (const float2*)b1, (float2*)h, N, 1);

    // layer 2 (reuse xl/xr)
    dual_gemm128_kernel<<<dual_blocks, 256, 0, stream>>>(
        (const float4*)h, (const float4*)Wl2, (const float4*)bl2,
        (const float4*)Wr2, (const float4*)br2, (float4*)xl, (float4*)xr, N);
    gat_edge_kernel<<<edge_blocks, eb, 0, stream>>>((const float2*)xl, (const float2*)xr,
                                                    srcs, row_ptr, (const float2*)att2,
                                                    (const float2*)b2, (float2*)d_out, N, 0);
}

// Round 5
// 396.978 us; speedup vs baseline: 1.2469x; 1.2469x over previous
//
#include <hip/hip_runtime.h>
#include <hip/hip_bf16.h>
#include <float.h>

#define F 128          // hidden = H*C
#define HEADS 4
#define CPH 32

// ---------------- CSR build ----------------

__global__ void count_deg_kernel(const int* __restrict__ dst, int* __restrict__ deg, int E) {
    int i = blockIdx.x * blockDim.x + threadIdx.x;
    if (i < E) atomicAdd(&deg[dst[i]], 1);
}

__global__ __launch_bounds__(1024) void scan1_kernel(const int* __restrict__ deg,
                                                     int* __restrict__ excl,
                                                     int* __restrict__ bsums, int n) {
    __shared__ int tmp[1024];
    int i = blockIdx.x * 1024 + threadIdx.x;
    int v = (i < n) ? deg[i] : 0;
    tmp[threadIdx.x] = v;
    __syncthreads();
    for (int o = 1; o < 1024; o <<= 1) {
        int a = (threadIdx.x >= o) ? tmp[threadIdx.x - o] : 0;
        __syncthreads();
        tmp[threadIdx.x] += a;
        __syncthreads();
    }
    if (i < n) excl[i] = tmp[threadIdx.x] - v;
    if (threadIdx.x == 1023) bsums[blockIdx.x] = tmp[1023];
}

__global__ __launch_bounds__(1024) void scan2_kernel(int* __restrict__ bsums, int nb) {
    __shared__ int tmp[1024];
    int v = (threadIdx.x < nb) ? bsums[threadIdx.x] : 0;
    tmp[threadIdx.x] = v;
    __syncthreads();
    for (int o = 1; o < 1024; o <<= 1) {
        int a = (threadIdx.x >= o) ? tmp[threadIdx.x - o] : 0;
        __syncthreads();
        tmp[threadIdx.x] += a;
        __syncthreads();
    }
    if (threadIdx.x < nb) bsums[threadIdx.x] = tmp[threadIdx.x] - v;  // exclusive
}

// writes row_ptr and also initializes cursor = row start (scatter bumps it directly)
__global__ void scan3_kernel(const int* __restrict__ excl, const int* __restrict__ bsums,
                             int* __restrict__ row_ptr, int* __restrict__ cursor,
                             int n, int E) {
    int i = blockIdx.x * 256 + threadIdx.x;
    if (i < n) {
        int v = excl[i] + bsums[i >> 10];
        row_ptr[i] = v;
        cursor[i] = v;
    }
    if (i == n) row_ptr[n] = E;
}

__global__ void scatter_kernel(const int* __restrict__ src, const int* __restrict__ dst,
                               int* __restrict__ cursor, int* __restrict__ srcs, int E) {
    int i = blockIdx.x * blockDim.x + threadIdx.x;
    if (i < E) {
        int pos = atomicAdd(&cursor[dst[i]], 1);
        srcs[pos] = src[i];
    }
}

// ---------------- dual fp32 GEMM: Y1 = X@W1+b1, Y2 = X@W2+b2 ----------------
// Both W in LDS (128KB), 1024 thr/block (16 waves/CU, 50% occupancy at 1 block/CU),
// 8 rows/thread, 256 rows/block. LDS traffic = 4KB/thread (amortized over 8 rows).

__global__ __launch_bounds__(1024, 4) void dual_gemm128_kernel(
    const float4* __restrict__ X4,
    const float4* __restrict__ W14, const float4* __restrict__ b14,
    const float4* __restrict__ W24, const float4* __restrict__ b24,
    float4* __restrict__ Y14, float4* __restrict__ Y24, int N)
{
    __shared__ float4 Ws1[F * F / 4];   // 64KB
    __shared__ float4 Ws2[F * F / 4];   // 64KB
    for (int i = threadIdx.x; i < F * F / 4; i += 1024) {
        Ws1[i] = W14[i];
        Ws2[i] = W24[i];
    }
    __syncthreads();

    const int cl  = threadIdx.x & 31;        // output col-quad 4cl..4cl+3
    const int grp = threadIdx.x >> 5;        // 0..31, 8 rows each
    const int row0 = blockIdx.x * 256 + grp * 8;

    float4 a1[8], a2[8];
    #pragma unroll
    for (int i = 0; i < 8; ++i) {
        a1[i] = make_float4(0.f, 0.f, 0.f, 0.f);
        a2[i] = make_float4(0.f, 0.f, 0.f, 0.f);
    }
    int r[8];
    #pragma unroll
    for (int i = 0; i < 8; ++i) {
        int rr = row0 + i;
        r[i] = rr < N ? rr : N - 1;          // clamp loads, guard stores
    }

    for (int kc = 0; kc < 32; ++kc) {        // k-chunks of 4
        float4 xv[8];
        #pragma unroll
        for (int i = 0; i < 8; ++i)
            xv[i] = X4[(size_t)r[i] * 32 + kc];
        #pragma unroll
        for (int kk = 0; kk < 4; ++kk) {
            float4 w1 = Ws1[(4 * kc + kk) * 32 + cl];
            float4 w2 = Ws2[(4 * kc + kk) * 32 + cl];
            #pragma unroll
            for (int i = 0; i < 8; ++i) {
                float xs = ((const float*)&xv[i])[kk];
                a1[i].x = fmaf(xs, w1.x, a1[i].x);
                a1[i].y = fmaf(xs, w1.y, a1[i].y);
                a1[i].z = fmaf(xs, w1.z, a1[i].z);
                a1[i].w = fmaf(xs, w1.w, a1[i].w);
                a2[i].x = fmaf(xs, w2.x, a2[i].x);
                a2[i].y = fmaf(xs, w2.y, a2[i].y);
                a2[i].z = fmaf(xs, w2.z, a2[i].z);
                a2[i].w = fmaf(xs, w2.w, a2[i].w);
            }
        }
    }

    float4 bi1 = b14[cl];
    float4 bi2 = b24[cl];
    #pragma unroll
    for (int i = 0; i < 8; ++i) {
        if (row0 + i < N) {
            float4 o1, o2;
            o1.x = a1[i].x + bi1.x; o1.y = a1[i].y + bi1.y;
            o1.z = a1[i].z + bi1.z; o1.w = a1[i].w + bi1.w;
            o2.x = a2[i].x + bi2.x; o2.y = a2[i].y + bi2.y;
            o2.z = a2[i].z + bi2.z; o2.w = a2[i].w + bi2.w;
            Y14[(size_t)(row0 + i) * 32 + cl] = o1;
            Y24[(size_t)(row0 + i) * 32 + cl] = o2;
        }
    }
}

// ---------------- fused edge phase ----------------
// 1 wave/node. Lane: cl = l&31 owns channel-quad 4cl..4cl+3 (float4, 16B gather),
// half = l>>5 handles even/odd edges -> 2 edges per "chain step".
// 4 explicit independent chains (8 edges in flight). Head = 8-lane group, 3-step shfl.
// Plain exp (logits O(5), fp32-safe; identical math to max-subtracted softmax).

__device__ __forceinline__ float logit4(float4 v, float4 xr_t, float4 a_t) {
    float e0 = v.x + xr_t.x; e0 = e0 >= 0.f ? e0 : 0.2f * e0;
    float e1 = v.y + xr_t.y; e1 = e1 >= 0.f ? e1 : 0.2f * e1;
    float e2 = v.z + xr_t.z; e2 = e2 >= 0.f ? e2 : 0.2f * e2;
    float e3 = v.w + xr_t.w; e3 = e3 >= 0.f ? e3 : 0.2f * e3;
    float p = fmaf(e3, a_t.w, fmaf(e2, a_t.z, fmaf(e1, a_t.y, e0 * a_t.x)));
    p += __shfl_xor(p, 4);
    p += __shfl_xor(p, 2);
    p += __shfl_xor(p, 1);
    return p;
}

__global__ __launch_bounds__(256) void gat_edge_kernel(
    const float4* __restrict__ xl4, const float4* __restrict__ xr4,
    const int* __restrict__ srcs, const int* __restrict__ row_ptr,
    const float4* __restrict__ att4, const float4* __restrict__ bias4,
    float4* __restrict__ out4, int N, int do_relu)
{
    int node = blockIdx.x * 4 + threadIdx.y;
    if (node >= N) return;
    int lane = threadIdx.x;        // 0..63
    int cl   = lane & 31;
    int half = lane >> 5;
    float4 xr_t = xr4[(size_t)node * 32 + cl];
    float4 a_t  = att4[cl];
    int beg = row_ptr[node], end = row_ptr[node + 1];
    float s = 0.f, o0 = 0.f, o1 = 0.f, o2 = 0.f, o3 = 0.f;

    int i = beg;
    for (; i + 8 <= end; i += 8) {           // 8 edges: this half does i+half+{0,2,4,6}
        int sn0 = srcs[i + half];
        int sn1 = srcs[i + half + 2];
        int sn2 = srcs[i + half + 4];
        int sn3 = srcs[i + half + 6];
        float4 v0 = xl4[(size_t)sn0 * 32 + cl];
        float4 v1 = xl4[(size_t)sn1 * 32 + cl];
        float4 v2 = xl4[(size_t)sn2 * 32 + cl];
        float4 v3 = xl4[(size_t)sn3 * 32 + cl];
        float p0 = logit4(v0, xr_t, a_t);
        float p1 = logit4(v1, xr_t, a_t);
        float p2 = logit4(v2, xr_t, a_t);
        float p3 = logit4(v3, xr_t, a_t);
        float w0 = __expf(p0), w1 = __expf(p1), w2 = __expf(p2), w3 = __expf(p3);
        s += (w0 + w1) + (w2 + w3);
        o0 = fmaf(w0, v0.x, o0); o1 = fmaf(w0, v0.y, o1); o2 = fmaf(w0, v0.z, o2); o3 = fmaf(w0, v0.w, o3);
        o0 = fmaf(w1, v1.x, o0); o1 = fmaf(w1, v1.y, o1); o2 = fmaf(w1, v1.z, o2); o3 = fmaf(w1, v1.w, o3);
        o0 = fmaf(w2, v2.x, o0); o1 = fmaf(w2, v2.y, o1); o2 = fmaf(w2, v2.z, o2); o3 = fmaf(w2, v2.w, o3);
        o0 = fmaf(w3, v3.x, o0); o1 = fmaf(w3, v3.y, o1); o2 = fmaf(w3, v3.z, o2); o3 = fmaf(w3, v3.w, o3);
    }
    for (; i + 2 <= end; i += 2) {           // pairs: this half does edge i+half
        int sn = srcs[i + half];
        float4 v = xl4[(size_t)sn * 32 + cl];
        float p = logit4(v, xr_t, a_t);
        float w = __expf(p);
        s += w;
        o0 = fmaf(w, v.x, o0); o1 = fmaf(w, v.y, o1);
        o2 = fmaf(w, v.z, o2); o3 = fmaf(w, v.w, o3);
    }
    if (i < end) {                           // single leftover edge: half 0 only
        int sn = srcs[i];
        float4 v = xl4[(size_t)sn * 32 + cl];
        float p = logit4(v, xr_t, a_t);
        float w = (half == 0) ? __expf(p) : 0.f;
        s += w;
        o0 = fmaf(w, v.x, o0); o1 = fmaf(w, v.y, o1);
        o2 = fmaf(w, v.z, o2); o3 = fmaf(w, v.w, o3);
    }
    // combine even/odd halves
    s  += __shfl_xor(s, 32);
    o0 += __shfl_xor(o0, 32);
    o1 += __shfl_xor(o1, 32);
    o2 += __shfl_xor(o2, 32);
    o3 += __shfl_xor(o3, 32);
    if (half == 0) {
        float inv = 1.f / (s + 1e-16f);
        float4 bi = bias4[cl];
        float4 rr;
        rr.x = fmaf(o0, inv, bi.x);
        rr.y = fmaf(o1, inv, bi.y);
        rr.z = fmaf(o2, inv, bi.z);
        rr.w = fmaf(o3, inv, bi.w);
        if (do_relu) {
            rr.x = fmaxf(rr.x, 0.f); rr.y = fmaxf(rr.y, 0.f);
            rr.z = fmaxf(rr.z, 0.f); rr.w = fmaxf(rr.w, 0.f);
        }
        out4[(size_t)node * 32 + cl] = rr;
    }
}

// ---------------- launch ----------------

extern "C" void kernel_launch(void* const* d_in, const int* in_sizes, int n_in,
                              void* d_out, int out_size, void* d_ws, size_t ws_size,
                              hipStream_t stream)
{
    const float* x    = (const float*)d_in[0];
    const int*   ei   = (const int*)d_in[1];
    const float* Wl1  = (const float*)d_in[2];
    const float* Wr1  = (const float*)d_in[3];
    const float* Wl2  = (const float*)d_in[4];
    const float* Wr2  = (const float*)d_in[5];
    const float* bl1  = (const float*)d_in[6];
    const float* br1  = (const float*)d_in[7];
    const float* bl2  = (const float*)d_in[8];
    const float* br2  = (const float*)d_in[9];
    const float* att1 = (const float*)d_in[10];
    const float* att2 = (const float*)d_in[11];
    const float* b1   = (const float*)d_in[12];
    const float* b2   = (const float*)d_in[13];

    const int N = in_sizes[0] / F;
    const int E = in_sizes[1] / 2;
    const int* src = ei;
    const int* dst = ei + E;

    char* ws = (char*)d_ws;
    size_t off = 0;
    auto alloc = [&](size_t bytes) -> void* {
        void* p = ws + off;
        off = (off + bytes + 255) & ~(size_t)255;
        return p;
    };
    float* xl      = (float*)alloc((size_t)N * F * sizeof(float));
    float* xr      = (float*)alloc((size_t)N * F * sizeof(float));
    float* h       = (float*)alloc((size_t)N * F * sizeof(float));
    int*   row_ptr = (int*)alloc((size_t)(N + 1) * sizeof(int));
    int*   deg     = (int*)alloc((size_t)N * sizeof(int));
    int*   excl    = (int*)alloc((size_t)N * sizeof(int));
    int*   bsums   = (int*)alloc((size_t)1024 * sizeof(int));
    int*   cursor  = (int*)alloc((size_t)N * sizeof(int));
    int*   srcs    = (int*)alloc((size_t)E * sizeof(int));

    // CSR build (edge structure shared by both layers)
    hipMemsetAsync(deg, 0, (size_t)N * sizeof(int), stream);
    count_deg_kernel<<<(E + 255) / 256, 256, 0, stream>>>(dst, deg, E);
    const int nchunks = (N + 1023) / 1024;
    scan1_kernel<<<nchunks, 1024, 0, stream>>>(deg, excl, bsums, N);
    scan2_kernel<<<1, 1024, 0, stream>>>(bsums, nchunks);
    scan3_kernel<<<(N + 256) / 256, 256, 0, stream>>>(excl, bsums, row_ptr, cursor, N, E);
    scatter_kernel<<<(E + 255) / 256, 256, 0, stream>>>(src, dst, cursor, srcs, E);

    const int dual_blocks = (N + 255) / 256;
    dim3 eb(64, 4);
    const int edge_blocks = (N + 3) / 4;

    // layer 1
    dual_gemm128_kernel<<<dual_blocks, 1024, 0, stream>>>(
        (const float4*)x, (const float4*)Wl1, (const float4*)bl1,
        (const float4*)Wr1, (const float4*)br1, (float4*)xl, (float4*)xr, N);
    gat_edge_kernel<<<edge_blocks, eb, 0, stream>>>((const float4*)xl, (const float4*)xr,
                                                    srcs, row_ptr, (const float4*)att1,
                                                    (const float4*)b1, (float4*)h, N, 1);

    // layer 2 (reuse xl/xr)
    dual_gemm128_kernel<<<dual_blocks, 1024, 0, stream>>>(
        (const float4*)h, (const float4*)Wl2, (const float4*)bl2,
        (const float4*)Wr2, (const float4*)br2, (float4*)xl, (float4*)xr, N);
    gat_edge_kernel<<<edge_blocks, eb, 0, stream>>>((const float4*)xl, (const float4*)xr,
                                                    srcs, row_ptr, (const float4*)att2,
                                                    (const float4*)b2, (float4*)d_out, N, 0);
}

// Round 6
// 371.507 us; speedup vs baseline: 1.3324x; 1.0686x over previous
//
#include <hip/hip_runtime.h>
#include <hip/hip_bf16.h>
#include <float.h>

#define F 128          // hidden = H*C
#define HEADS 4
#define CPH 32

// ---------------- CSR build ----------------

__global__ void count_deg_kernel(const int* __restrict__ dst, int* __restrict__ deg, int E) {
    int i = blockIdx.x * blockDim.x + threadIdx.x;
    if (i < E) atomicAdd(&deg[dst[i]], 1);
}

__global__ __launch_bounds__(1024) void scan1_kernel(const int* __restrict__ deg,
                                                     int* __restrict__ excl,
                                                     int* __restrict__ bsums, int n) {
    __shared__ int tmp[1024];
    int i = blockIdx.x * 1024 + threadIdx.x;
    int v = (i < n) ? deg[i] : 0;
    tmp[threadIdx.x] = v;
    __syncthreads();
    for (int o = 1; o < 1024; o <<= 1) {
        int a = (threadIdx.x >= o) ? tmp[threadIdx.x - o] : 0;
        __syncthreads();
        tmp[threadIdx.x] += a;
        __syncthreads();
    }
    if (i < n) excl[i] = tmp[threadIdx.x] - v;
    if (threadIdx.x == 1023) bsums[blockIdx.x] = tmp[1023];
}

__global__ __launch_bounds__(1024) void scan2_kernel(int* __restrict__ bsums, int nb) {
    __shared__ int tmp[1024];
    int v = (threadIdx.x < nb) ? bsums[threadIdx.x] : 0;
    tmp[threadIdx.x] = v;
    __syncthreads();
    for (int o = 1; o < 1024; o <<= 1) {
        int a = (threadIdx.x >= o) ? tmp[threadIdx.x - o] : 0;
        __syncthreads();
        tmp[threadIdx.x] += a;
        __syncthreads();
    }
    if (threadIdx.x < nb) bsums[threadIdx.x] = tmp[threadIdx.x] - v;  // exclusive
}

// writes row_ptr and also initializes cursor = row start (scatter bumps it directly)
__global__ void scan3_kernel(const int* __restrict__ excl, const int* __restrict__ bsums,
                             int* __restrict__ row_ptr, int* __restrict__ cursor,
                             int n, int E) {
    int i = blockIdx.x * 256 + threadIdx.x;
    if (i < n) {
        int v = excl[i] + bsums[i >> 10];
        row_ptr[i] = v;
        cursor[i] = v;
    }
    if (i == n) row_ptr[n] = E;
}

__global__ void scatter_kernel(const int* __restrict__ src, const int* __restrict__ dst,
                               int* __restrict__ cursor, int* __restrict__ srcs, int E) {
    int i = blockIdx.x * blockDim.x + threadIdx.x;
    if (i < E) {
        int pos = atomicAdd(&cursor[dst[i]], 1);
        srcs[pos] = src[i];
    }
}

// ---------------- fp32 GEMM: Y = X@W + b ----------------
// W in LDS (64KB), 512 thr/block -> 2 blocks/CU (16 waves/CU).
// 8 rows/thread, 128 rows/block. VGPR ~80 (acc 32 + xv 32 + w 4) -> no spill at
// the 128-VGPR cap from __launch_bounds__(512,4).

__global__ __launch_bounds__(512, 4) void gemm128_kernel(
    const float4* __restrict__ X4, const float4* __restrict__ W4,
    const float4* __restrict__ b4, float4* __restrict__ Y4, int N)
{
    __shared__ float4 Ws[F * F / 4];   // 64KB
    for (int i = threadIdx.x; i < F * F / 4; i += 512) Ws[i] = W4[i];
    __syncthreads();

    const int cl  = threadIdx.x & 31;        // output col-quad 4cl..4cl+3
    const int grp = threadIdx.x >> 5;        // 0..15, 8 rows each
    const int row0 = blockIdx.x * 128 + grp * 8;

    float4 acc[8];
    #pragma unroll
    for (int i = 0; i < 8; ++i) acc[i] = make_float4(0.f, 0.f, 0.f, 0.f);
    int r[8];
    #pragma unroll
    for (int i = 0; i < 8; ++i) {
        int rr = row0 + i;
        r[i] = rr < N ? rr : N - 1;          // clamp loads, guard stores
    }

    for (int kc = 0; kc < 32; ++kc) {        // k-chunks of 4
        float4 xv[8];
        #pragma unroll
        for (int i = 0; i < 8; ++i)
            xv[i] = X4[(size_t)r[i] * 32 + kc];
        #pragma unroll
        for (int kk = 0; kk < 4; ++kk) {
            float4 w = Ws[(4 * kc + kk) * 32 + cl];
            #pragma unroll
            for (int i = 0; i < 8; ++i) {
                float xs = ((const float*)&xv[i])[kk];
                acc[i].x = fmaf(xs, w.x, acc[i].x);
                acc[i].y = fmaf(xs, w.y, acc[i].y);
                acc[i].z = fmaf(xs, w.z, acc[i].z);
                acc[i].w = fmaf(xs, w.w, acc[i].w);
            }
        }
    }

    float4 bi = b4[cl];
    #pragma unroll
    for (int i = 0; i < 8; ++i) {
        if (row0 + i < N) {
            float4 o;
            o.x = acc[i].x + bi.x; o.y = acc[i].y + bi.y;
            o.z = acc[i].z + bi.z; o.w = acc[i].w + bi.w;
            Y4[(size_t)(row0 + i) * 32 + cl] = o;
        }
    }
}

// ---------------- fused edge phase (R2-proven structure) ----------------
// 1 wave per node; thread t owns channels (2t, 2t+1); head group = 16 lanes.
// Plain exp (logits O(5), exp-safe in fp32, math-identical to max-subtracted form).
// 4 independent gather->dot->shfl chains in flight per iteration.

__device__ __forceinline__ float edge_logit(float2 v, float2 xr_t, float2 a_t) {
    float e0 = v.x + xr_t.x; e0 = e0 >= 0.f ? e0 : 0.2f * e0;
    float e1 = v.y + xr_t.y; e1 = e1 >= 0.f ? e1 : 0.2f * e1;
    float p = e0 * a_t.x + e1 * a_t.y;
    p += __shfl_xor(p, 8);   // reduce over 16-lane head group
    p += __shfl_xor(p, 4);
    p += __shfl_xor(p, 2);
    p += __shfl_xor(p, 1);
    return p;
}

__global__ __launch_bounds__(256) void gat_edge_kernel(
    const float2* __restrict__ xl2, const float2* __restrict__ xr2,
    const int* __restrict__ srcs, const int* __restrict__ row_ptr,
    const float2* __restrict__ att2, const float2* __restrict__ bias2,
    float2* __restrict__ out2, int N, int do_relu)
{
    int node = blockIdx.x * 4 + threadIdx.y;
    int t = threadIdx.x;                       // 0..63
    if (node >= N) return;
    float2 xr_t = xr2[(size_t)node * 64 + t];
    float2 a_t  = att2[t];
    int beg = row_ptr[node], end = row_ptr[node + 1];
    float s = 0.f;
    float ox = 0.f, oy = 0.f;
    int i = beg;
    for (; i + 4 <= end; i += 4) {
        int sn0 = srcs[i], sn1 = srcs[i + 1], sn2 = srcs[i + 2], sn3 = srcs[i + 3];
        float2 v0 = xl2[(size_t)sn0 * 64 + t];
        float2 v1 = xl2[(size_t)sn1 * 64 + t];
        float2 v2 = xl2[(size_t)sn2 * 64 + t];
        float2 v3 = xl2[(size_t)sn3 * 64 + t];
        float p0 = edge_logit(v0, xr_t, a_t);
        float p1 = edge_logit(v1, xr_t, a_t);
        float p2 = edge_logit(v2, xr_t, a_t);
        float p3 = edge_logit(v3, xr_t, a_t);
        float w0 = __expf(p0), w1 = __expf(p1), w2 = __expf(p2), w3 = __expf(p3);
        s += (w0 + w1) + (w2 + w3);
        ox = fmaf(w0, v0.x, ox); oy = fmaf(w0, v0.y, oy);
        ox = fmaf(w1, v1.x, ox); oy = fmaf(w1, v1.y, oy);
        ox = fmaf(w2, v2.x, ox); oy = fmaf(w2, v2.y, oy);
        ox = fmaf(w3, v3.x, ox); oy = fmaf(w3, v3.y, oy);
    }
    for (; i < end; ++i) {
        int sn = srcs[i];
        float2 v = xl2[(size_t)sn * 64 + t];
        float p = edge_logit(v, xr_t, a_t);
        float w = __expf(p);
        s += w;
        ox = fmaf(w, v.x, ox); oy = fmaf(w, v.y, oy);
    }
    float inv = 1.f / (s + 1e-16f);
    float2 bi = bias2[t];
    float rx = ox * inv + bi.x;
    float ry = oy * inv + bi.y;
    if (do_relu) { rx = fmaxf(rx, 0.f); ry = fmaxf(ry, 0.f); }
    float2 rr; rr.x = rx; rr.y = ry;
    out2[(size_t)node * 64 + t] = rr;
}

// ---------------- launch ----------------

extern "C" void kernel_launch(void* const* d_in, const int* in_sizes, int n_in,
                              void* d_out, int out_size, void* d_ws, size_t ws_size,
                              hipStream_t stream)
{
    const float* x    = (const float*)d_in[0];
    const int*   ei   = (const int*)d_in[1];
    const float* Wl1  = (const float*)d_in[2];
    const float* Wr1  = (const float*)d_in[3];
    const float* Wl2  = (const float*)d_in[4];
    const float* Wr2  = (const float*)d_in[5];
    const float* bl1  = (const float*)d_in[6];
    const float* br1  = (const float*)d_in[7];
    const float* bl2  = (const float*)d_in[8];
    const float* br2  = (const float*)d_in[9];
    const float* att1 = (const float*)d_in[10];
    const float* att2 = (const float*)d_in[11];
    const float* b1   = (const float*)d_in[12];
    const float* b2   = (const float*)d_in[13];

    const int N = in_sizes[0] / F;
    const int E = in_sizes[1] / 2;
    const int* src = ei;
    const int* dst = ei + E;

    char* ws = (char*)d_ws;
    size_t off = 0;
    auto alloc = [&](size_t bytes) -> void* {
        void* p = ws + off;
        off = (off + bytes + 255) & ~(size_t)255;
        return p;
    };
    float* xl      = (float*)alloc((size_t)N * F * sizeof(float));
    float* xr      = (float*)alloc((size_t)N * F * sizeof(float));
    float* h       = (float*)alloc((size_t)N * F * sizeof(float));
    int*   row_ptr = (int*)alloc((size_t)(N + 1) * sizeof(int));
    int*   deg     = (int*)alloc((size_t)N * sizeof(int));
    int*   excl    = (int*)alloc((size_t)N * sizeof(int));
    int*   bsums   = (int*)alloc((size_t)1024 * sizeof(int));
    int*   cursor  = (int*)alloc((size_t)N * sizeof(int));
    int*   srcs    = (int*)alloc((size_t)E * sizeof(int));

    // CSR build (edge structure shared by both layers)
    hipMemsetAsync(deg, 0, (size_t)N * sizeof(int), stream);
    count_deg_kernel<<<(E + 255) / 256, 256, 0, stream>>>(dst, deg, E);
    const int nchunks = (N + 1023) / 1024;
    scan1_kernel<<<nchunks, 1024, 0, stream>>>(deg, excl, bsums, N);
    scan2_kernel<<<1, 1024, 0, stream>>>(bsums, nchunks);
    scan3_kernel<<<(N + 256) / 256, 256, 0, stream>>>(excl, bsums, row_ptr, cursor, N, E);
    scatter_kernel<<<(E + 255) / 256, 256, 0, stream>>>(src, dst, cursor, srcs, E);

    const int gemm_blocks = (N + 127) / 128;
    dim3 eb(64, 4);
    const int edge_blocks = (N + 3) / 4;

    // layer 1
    gemm128_kernel<<<gemm_blocks, 512, 0, stream>>>(
        (const float4*)x, (const float4*)Wl1, (const float4*)bl1, (float4*)xl, N);
    gemm128_kernel<<<gemm_blocks, 512, 0, stream>>>(
        (const float4*)x, (const float4*)Wr1, (const float4*)br1, (float4*)xr, N);
    gat_edge_kernel<<<edge_blocks, eb, 0, stream>>>((const float2*)xl, (const float2*)xr,
                                                    srcs, row_ptr, (const float2*)att1,
                                                    (const float2*)b1, (float2*)h, N, 1);

    // layer 2 (reuse xl/xr)
    gemm128_kernel<<<gemm_blocks, 512, 0, stream>>>(
        (const float4*)h, (const float4*)Wl2, (const float4*)bl2, (float4*)xl, N);
    gemm128_kernel<<<gemm_blocks, 512, 0, stream>>>(
        (const float4*)h, (const float4*)Wr2, (const float4*)br2, (float4*)xr, N);
    gat_edge_kernel<<<edge_blocks, eb, 0, stream>>>((const float2*)xl, (const float2*)xr,
                                                    srcs, row_ptr, (const float2*)att2,
                                                    (const float2*)b2, (float2*)d_out, N, 0);
}

// Round 7
// 363.511 us; speedup vs baseline: 1.3617x; 1.0220x over previous
//
#include <hip/hip_runtime.h>
#include <hip/hip_bf16.h>
#include <hip/hip_fp16.h>
#include <float.h>

#define F 128          // hidden = H*C
#define HEADS 4
#define CPH 32

// ---------------- CSR build ----------------

__global__ void count_deg_kernel(const int* __restrict__ dst, int* __restrict__ deg, int E) {
    int i = blockIdx.x * blockDim.x + threadIdx.x;
    if (i < E) atomicAdd(&deg[dst[i]], 1);
}

__global__ __launch_bounds__(1024) void scan1_kernel(const int* __restrict__ deg,
                                                     int* __restrict__ excl,
                                                     int* __restrict__ bsums, int n) {
    __shared__ int tmp[1024];
    int i = blockIdx.x * 1024 + threadIdx.x;
    int v = (i < n) ? deg[i] : 0;
    tmp[threadIdx.x] = v;
    __syncthreads();
    for (int o = 1; o < 1024; o <<= 1) {
        int a = (threadIdx.x >= o) ? tmp[threadIdx.x - o] : 0;
        __syncthreads();
        tmp[threadIdx.x] += a;
        __syncthreads();
    }
    if (i < n) excl[i] = tmp[threadIdx.x] - v;
    if (threadIdx.x == 1023) bsums[blockIdx.x] = tmp[1023];
}

__global__ __launch_bounds__(1024) void scan2_kernel(int* __restrict__ bsums, int nb) {
    __shared__ int tmp[1024];
    int v = (threadIdx.x < nb) ? bsums[threadIdx.x] : 0;
    tmp[threadIdx.x] = v;
    __syncthreads();
    for (int o = 1; o < 1024; o <<= 1) {
        int a = (threadIdx.x >= o) ? tmp[threadIdx.x - o] : 0;
        __syncthreads();
        tmp[threadIdx.x] += a;
        __syncthreads();
    }
    if (threadIdx.x < nb) bsums[threadIdx.x] = tmp[threadIdx.x] - v;  // exclusive
}

// writes row_ptr and also initializes cursor = row start (scatter bumps it directly)
__global__ void scan3_kernel(const int* __restrict__ excl, const int* __restrict__ bsums,
                             int* __restrict__ row_ptr, int* __restrict__ cursor,
                             int n, int E) {
    int i = blockIdx.x * 256 + threadIdx.x;
    if (i < n) {
        int v = excl[i] + bsums[i >> 10];
        row_ptr[i] = v;
        cursor[i] = v;
    }
    if (i == n) row_ptr[n] = E;
}

__global__ void scatter_kernel(const int* __restrict__ src, const int* __restrict__ dst,
                               int* __restrict__ cursor, int* __restrict__ srcs, int E) {
    int i = blockIdx.x * blockDim.x + threadIdx.x;
    if (i < E) {
        int pos = atomicAdd(&cursor[dst[i]], 1);
        srcs[pos] = src[i];
    }
}

// ---------------- fp32 GEMM: Y = X@W + b ----------------
// W staged in TWO 32KB k-strips (64 k-rows each) -> 256-thr blocks, 64 rows/block,
// 782 blocks ~ 3/CU evenly balanced (vs 64KB/512thr: 391 blocks, 2-blocks-LDS-cap,
// half the CUs got 2 blocks -> 1.33-2x imbalance). 8 rows/thread, ~90 VGPR, no spill.
// out_half != 0: write Y as fp16 (uint2 = 4 cols) for the edge-gather path.

__global__ __launch_bounds__(256) void gemm128_kernel(
    const float4* __restrict__ X4, const float4* __restrict__ W4,
    const float4* __restrict__ b4, float4* __restrict__ Yf,
    uint2* __restrict__ Yh, int N, int out_half)
{
    __shared__ float4 Ws[2048];              // 32KB: 64 k-rows x 128 cols
    const int cl  = threadIdx.x & 31;        // output col-quad 4cl..4cl+3
    const int grp = threadIdx.x >> 5;        // 0..7, 8 rows each
    const int row0 = blockIdx.x * 64 + grp * 8;

    float4 acc[8];
    #pragma unroll
    for (int i = 0; i < 8; ++i) acc[i] = make_float4(0.f, 0.f, 0.f, 0.f);
    int r[8];
    #pragma unroll
    for (int i = 0; i < 8; ++i) {
        int rr = row0 + i;
        r[i] = rr < N ? rr : N - 1;          // clamp loads, guard stores
    }

    for (int s = 0; s < 2; ++s) {            // two k-strips of 64
        __syncthreads();                     // previous strip's reads done
        for (int i = threadIdx.x; i < 2048; i += 256) Ws[i] = W4[s * 2048 + i];
        __syncthreads();
        for (int kc = 0; kc < 16; ++kc) {    // k-chunks of 4 within strip
            float4 xv[8];
            #pragma unroll
            for (int i = 0; i < 8; ++i)
                xv[i] = X4[(size_t)r[i] * 32 + s * 16 + kc];
            #pragma unroll
            for (int kk = 0; kk < 4; ++kk) {
                float4 w = Ws[(4 * kc + kk) * 32 + cl];
                #pragma unroll
                for (int i = 0; i < 8; ++i) {
                    float xs = ((const float*)&xv[i])[kk];
                    acc[i].x = fmaf(xs, w.x, acc[i].x);
                    acc[i].y = fmaf(xs, w.y, acc[i].y);
                    acc[i].z = fmaf(xs, w.z, acc[i].z);
                    acc[i].w = fmaf(xs, w.w, acc[i].w);
                }
            }
        }
    }

    float4 bi = b4[cl];
    #pragma unroll
    for (int i = 0; i < 8; ++i) {
        if (row0 + i < N) {
            float4 o;
            o.x = acc[i].x + bi.x; o.y = acc[i].y + bi.y;
            o.z = acc[i].z + bi.z; o.w = acc[i].w + bi.w;
            if (out_half) {
                __half2 h01 = __float22half2_rn(make_float2(o.x, o.y));
                __half2 h23 = __float22half2_rn(make_float2(o.z, o.w));
                uint2 u;
                u.x = *(unsigned int*)&h01;
                u.y = *(unsigned int*)&h23;
                Yh[(size_t)(row0 + i) * 32 + cl] = u;
            } else {
                Yf[(size_t)(row0 + i) * 32 + cl] = o;
            }
        }
    }
}

// ---------------- fused edge phase (R2-proven structure, fp16 xl gather) ----------------
// 1 wave per node; thread t owns channels (2t, 2t+1); head group = 16 lanes.
// xl stored fp16 (half gather bytes: 4B/lane, 256B/edge contiguous); fp32 compute.
// Plain exp (logits O(5), exp-safe in fp32, math-identical to max-subtracted form).
// 4 independent gather->dot->shfl chains in flight per iteration.

__device__ __forceinline__ float edge_logit(float2 v, float2 xr_t, float2 a_t) {
    float e0 = v.x + xr_t.x; e0 = e0 >= 0.f ? e0 : 0.2f * e0;
    float e1 = v.y + xr_t.y; e1 = e1 >= 0.f ? e1 : 0.2f * e1;
    float p = e0 * a_t.x + e1 * a_t.y;
    p += __shfl_xor(p, 8);   // reduce over 16-lane head group
    p += __shfl_xor(p, 4);
    p += __shfl_xor(p, 2);
    p += __shfl_xor(p, 1);
    return p;
}

__global__ __launch_bounds__(256) void gat_edge_kernel(
    const __half2* __restrict__ xlh, const float2* __restrict__ xr2,
    const int* __restrict__ srcs, const int* __restrict__ row_ptr,
    const float2* __restrict__ att2, const float2* __restrict__ bias2,
    float2* __restrict__ out2, int N, int do_relu)
{
    int node = blockIdx.x * 4 + threadIdx.y;
    int t = threadIdx.x;                       // 0..63
    if (node >= N) return;
    float2 xr_t = xr2[(size_t)node * 64 + t];
    float2 a_t  = att2[t];
    int beg = row_ptr[node], end = row_ptr[node + 1];
    float s = 0.f;
    float ox = 0.f, oy = 0.f;
    int i = beg;
    for (; i + 4 <= end; i += 4) {
        int sn0 = srcs[i], sn1 = srcs[i + 1], sn2 = srcs[i + 2], sn3 = srcs[i + 3];
        float2 v0 = __half22float2(xlh[(size_t)sn0 * 64 + t]);
        float2 v1 = __half22float2(xlh[(size_t)sn1 * 64 + t]);
        float2 v2 = __half22float2(xlh[(size_t)sn2 * 64 + t]);
        float2 v3 = __half22float2(xlh[(size_t)sn3 * 64 + t]);
        float p0 = edge_logit(v0, xr_t, a_t);
        float p1 = edge_logit(v1, xr_t, a_t);
        float p2 = edge_logit(v2, xr_t, a_t);
        float p3 = edge_logit(v3, xr_t, a_t);
        float w0 = __expf(p0), w1 = __expf(p1), w2 = __expf(p2), w3 = __expf(p3);
        s += (w0 + w1) + (w2 + w3);
        ox = fmaf(w0, v0.x, ox); oy = fmaf(w0, v0.y, oy);
        ox = fmaf(w1, v1.x, ox); oy = fmaf(w1, v1.y, oy);
        ox = fmaf(w2, v2.x, ox); oy = fmaf(w2, v2.y, oy);
        ox = fmaf(w3, v3.x, ox); oy = fmaf(w3, v3.y, oy);
    }
    for (; i < end; ++i) {
        int sn = srcs[i];
        float2 v = __half22float2(xlh[(size_t)sn * 64 + t]);
        float p = edge_logit(v, xr_t, a_t);
        float w = __expf(p);
        s += w;
        ox = fmaf(w, v.x, ox); oy = fmaf(w, v.y, oy);
    }
    float inv = 1.f / (s + 1e-16f);
    float2 bi = bias2[t];
    float rx = ox * inv + bi.x;
    float ry = oy * inv + bi.y;
    if (do_relu) { rx = fmaxf(rx, 0.f); ry = fmaxf(ry, 0.f); }
    float2 rr; rr.x = rx; rr.y = ry;
    out2[(size_t)node * 64 + t] = rr;
}

// ---------------- launch ----------------

extern "C" void kernel_launch(void* const* d_in, const int* in_sizes, int n_in,
                              void* d_out, int out_size, void* d_ws, size_t ws_size,
                              hipStream_t stream)
{
    const float* x    = (const float*)d_in[0];
    const int*   ei   = (const int*)d_in[1];
    const float* Wl1  = (const float*)d_in[2];
    const float* Wr1  = (const float*)d_in[3];
    const float* Wl2  = (const float*)d_in[4];
    const float* Wr2  = (const float*)d_in[5];
    const float* bl1  = (const float*)d_in[6];
    const float* br1  = (const float*)d_in[7];
    const float* bl2  = (const float*)d_in[8];
    const float* br2  = (const float*)d_in[9];
    const float* att1 = (const float*)d_in[10];
    const float* att2 = (const float*)d_in[11];
    const float* b1   = (const float*)d_in[12];
    const float* b2   = (const float*)d_in[13];

    const int N = in_sizes[0] / F;
    const int E = in_sizes[1] / 2;
    const int* src = ei;
    const int* dst = ei + E;

    char* ws = (char*)d_ws;
    size_t off = 0;
    auto alloc = [&](size_t bytes) -> void* {
        void* p = ws + off;
        off = (off + bytes + 255) & ~(size_t)255;
        return p;
    };
    __half2* xlh    = (__half2*)alloc((size_t)N * F * sizeof(__half));  // fp16 xl
    float*   xr     = (float*)alloc((size_t)N * F * sizeof(float));
    float*   h      = (float*)alloc((size_t)N * F * sizeof(float));
    int*   row_ptr  = (int*)alloc((size_t)(N + 1) * sizeof(int));
    int*   deg      = (int*)alloc((size_t)N * sizeof(int));
    int*   excl     = (int*)alloc((size_t)N * sizeof(int));
    int*   bsums    = (int*)alloc((size_t)1024 * sizeof(int));
    int*   cursor   = (int*)alloc((size_t)N * sizeof(int));
    int*   srcs     = (int*)alloc((size_t)E * sizeof(int));

    // CSR build (edge structure shared by both layers)
    hipMemsetAsync(deg, 0, (size_t)N * sizeof(int), stream);
    count_deg_kernel<<<(E + 255) / 256, 256, 0, stream>>>(dst, deg, E);
    const int nchunks = (N + 1023) / 1024;
    scan1_kernel<<<nchunks, 1024, 0, stream>>>(deg, excl, bsums, N);
    scan2_kernel<<<1, 1024, 0, stream>>>(bsums, nchunks);
    scan3_kernel<<<(N + 256) / 256, 256, 0, stream>>>(excl, bsums, row_ptr, cursor, N, E);
    scatter_kernel<<<(E + 255) / 256, 256, 0, stream>>>(src, dst, cursor, srcs, E);

    const int gemm_blocks = (N + 63) / 64;
    dim3 eb(64, 4);
    const int edge_blocks = (N + 3) / 4;

    // layer 1
    gemm128_kernel<<<gemm_blocks, 256, 0, stream>>>(
        (const float4*)x, (const float4*)Wl1, (const float4*)bl1,
        nullptr, (uint2*)xlh, N, 1);
    gemm128_kernel<<<gemm_blocks, 256, 0, stream>>>(
        (const float4*)x, (const float4*)Wr1, (const float4*)br1,
        (float4*)xr, nullptr, N, 0);
    gat_edge_kernel<<<edge_blocks, eb, 0, stream>>>(xlh, (const float2*)xr,
                                                    srcs, row_ptr, (const float2*)att1,
                                                    (const float2*)b1, (float2*)h, N, 1);

    // layer 2 (reuse xlh/xr)
    gemm128_kernel<<<gemm_blocks, 256, 0, stream>>>(
        (const float4*)h, (const float4*)Wl2, (const float4*)bl2,
        nullptr, (uint2*)xlh, N, 1);
    gemm128_kernel<<<gemm_blocks, 256, 0, stream>>>(
        (const float4*)h, (const float4*)Wr2, (const float4*)br2,
        (float4*)xr, nullptr, N, 0);
    gat_edge_kernel<<<edge_blocks, eb, 0, stream>>>(xlh, (const float2*)xr,
                                                    srcs, row_ptr, (const float2*)att2,
                                                    (const float2*)b2, (float2*)d_out, N, 0);
}

// Round 8
// 290.464 us; speedup vs baseline: 1.7041x; 1.2515x over previous
//
#include <hip/hip_runtime.h>
#include <hip/hip_bf16.h>
#include <hip/hip_fp16.h>
#include <float.h>

#define F 128          // hidden = H*C
#define HEADS 4
#define CPH 32

using f16x8 = __attribute__((ext_vector_type(8))) _Float16;
using f32x4 = __attribute__((ext_vector_type(4))) float;

// ---------------- CSR build ----------------

__global__ void count_deg_kernel(const int* __restrict__ dst, int* __restrict__ deg, int E) {
    int i = blockIdx.x * blockDim.x + threadIdx.x;
    if (i < E) atomicAdd(&deg[dst[i]], 1);
}

__global__ __launch_bounds__(1024) void scan1_kernel(const int* __restrict__ deg,
                                                     int* __restrict__ excl,
                                                     int* __restrict__ bsums, int n) {
    __shared__ int tmp[1024];
    int i = blockIdx.x * 1024 + threadIdx.x;
    int v = (i < n) ? deg[i] : 0;
    tmp[threadIdx.x] = v;
    __syncthreads();
    for (int o = 1; o < 1024; o <<= 1) {
        int a = (threadIdx.x >= o) ? tmp[threadIdx.x - o] : 0;
        __syncthreads();
        tmp[threadIdx.x] += a;
        __syncthreads();
    }
    if (i < n) excl[i] = tmp[threadIdx.x] - v;
    if (threadIdx.x == 1023) bsums[blockIdx.x] = tmp[1023];
}

__global__ __launch_bounds__(1024) void scan2_kernel(int* __restrict__ bsums, int nb) {
    __shared__ int tmp[1024];
    int v = (threadIdx.x < nb) ? bsums[threadIdx.x] : 0;
    tmp[threadIdx.x] = v;
    __syncthreads();
    for (int o = 1; o < 1024; o <<= 1) {
        int a = (threadIdx.x >= o) ? tmp[threadIdx.x - o] : 0;
        __syncthreads();
        tmp[threadIdx.x] += a;
        __syncthreads();
    }
    if (threadIdx.x < nb) bsums[threadIdx.x] = tmp[threadIdx.x] - v;  // exclusive
}

__global__ void scan3_kernel(const int* __restrict__ excl, const int* __restrict__ bsums,
                             int* __restrict__ row_ptr, int* __restrict__ cursor,
                             int n, int E) {
    int i = blockIdx.x * 256 + threadIdx.x;
    if (i < n) {
        int v = excl[i] + bsums[i >> 10];
        row_ptr[i] = v;
        cursor[i] = v;
    }
    if (i == n) row_ptr[n] = E;
}

__global__ void scatter_kernel(const int* __restrict__ src, const int* __restrict__ dst,
                               int* __restrict__ cursor, int* __restrict__ srcs, int E) {
    int i = blockIdx.x * blockDim.x + threadIdx.x;
    if (i < E) {
        int pos = atomicAdd(&cursor[dst[i]], 1);
        srcs[pos] = src[i];
    }
}

// ---------------- converts ----------------

// x fp32 -> fp16, 8 elems/thread
__global__ void convx_kernel(const float4* __restrict__ X4, f16x8* __restrict__ Xh, int n8) {
    int i = blockIdx.x * 256 + threadIdx.x;
    if (i < n8) {
        float4 a = X4[2 * i];
        float4 b = X4[2 * i + 1];
        f16x8 o;
        o[0] = (_Float16)a.x; o[1] = (_Float16)a.y; o[2] = (_Float16)a.z; o[3] = (_Float16)a.w;
        o[4] = (_Float16)b.x; o[5] = (_Float16)b.y; o[6] = (_Float16)b.z; o[7] = (_Float16)b.w;
        Xh[i] = o;
    }
}

// W[k][n] fp32 -> Wt[n][k] fp16, 4 matrices. 256 blocks (64/matrix) x 256 thr.
__global__ void convw_kernel(const float* __restrict__ W0, const float* __restrict__ W1,
                             const float* __restrict__ W2, const float* __restrict__ W3,
                             _Float16* __restrict__ T0, _Float16* __restrict__ T1,
                             _Float16* __restrict__ T2, _Float16* __restrict__ T3) {
    int m   = blockIdx.x >> 6;
    int tid = (blockIdx.x & 63) * 256 + threadIdx.x;   // 0..16383 = n*128+k
    int n = tid >> 7, k = tid & 127;
    const float* W = m == 0 ? W0 : m == 1 ? W1 : m == 2 ? W2 : W3;
    _Float16*    T = m == 0 ? T0 : m == 1 ? T1 : m == 2 ? T2 : T3;
    T[tid] = (_Float16)W[k * F + n];
}

// ---------------- dual MFMA GEMM: xl = Xh@Wl+bl (fp16 out), xr = Xh@Wr+br (fp32 out) ----
// mfma_f32_16x16x32_f16. Wave handles 16 rows x 128 cols; 4 waves/block = 64 rows.
// A/B both loaded as contiguous 8xfp16 with the SAME k-slot map (k = t*32+g*8+j) --
// only A/B consistency matters; C/D layout (col=lane&15, row=(lane>>4)*4+reg) is exact.
// No LDS; W^T frags are L1/L2-broadcast. C guard handles N tail (A rows clamped).

__global__ __launch_bounds__(256) void mfma_dual_gemm_kernel(
    const _Float16* __restrict__ Xh,
    const _Float16* __restrict__ Wlt, const float* __restrict__ bl,
    const _Float16* __restrict__ Wrt, const float* __restrict__ br,
    _Float16* __restrict__ xl, float* __restrict__ xr, int N)
{
    const int wave = threadIdx.x >> 6;
    const int lane = threadIdx.x & 63;
    const int row0 = blockIdx.x * 64 + wave * 16;
    const int arow = lane & 15;
    const int g    = lane >> 4;            // 0..3

    int xrow = row0 + arow;
    if (xrow >= N) xrow = N - 1;           // clamp (C stores guarded)
    const _Float16* xp = Xh + (size_t)xrow * F + g * 8;

    f16x8 afrag[4];
    #pragma unroll
    for (int t = 0; t < 4; ++t)
        afrag[t] = *(const f16x8*)(xp + t * 32);

    f32x4 accL[8], accR[8];
    #pragma unroll
    for (int nt = 0; nt < 8; ++nt) {
        accL[nt] = (f32x4){0.f, 0.f, 0.f, 0.f};
        accR[nt] = (f32x4){0.f, 0.f, 0.f, 0.f};
    }

    #pragma unroll
    for (int t = 0; t < 4; ++t) {
        #pragma unroll
        for (int nt = 0; nt < 8; ++nt) {
            const size_t boff = (size_t)(nt * 16 + arow) * F + t * 32 + g * 8;
            f16x8 bL = *(const f16x8*)(Wlt + boff);
            f16x8 bR = *(const f16x8*)(Wrt + boff);
            accL[nt] = __builtin_amdgcn_mfma_f32_16x16x32_f16(afrag[t], bL, accL[nt], 0, 0, 0);
            accR[nt] = __builtin_amdgcn_mfma_f32_16x16x32_f16(afrag[t], bR, accR[nt], 0, 0, 0);
        }
    }

    #pragma unroll
    for (int nt = 0; nt < 8; ++nt) {
        int ccol = nt * 16 + (lane & 15);
        float bLv = bl[ccol];
        float bRv = br[ccol];
        #pragma unroll
        for (int r2 = 0; r2 < 4; ++r2) {
            int crow = row0 + (lane >> 4) * 4 + r2;
            if (crow < N) {
                float vL = accL[nt][r2] + bLv;
                float vR = accR[nt][r2] + bRv;
                xl[(size_t)crow * F + ccol] = (_Float16)vL;
                xr[(size_t)crow * F + ccol] = vR;
            }
        }
    }
}

// ---------------- fused edge phase (R7 structure, fp16 xl gather) ----------------
// 1 wave per node; thread t owns channels (2t, 2t+1); head group = 16 lanes.
// Plain exp (logits O(5), exp-safe in fp32). 4 independent chains in flight.
// out_half: layer-1 writes fp16 h (feeds layer-2 MFMA GEMM directly).

__device__ __forceinline__ float edge_logit(float2 v, float2 xr_t, float2 a_t) {
    float e0 = v.x + xr_t.x; e0 = e0 >= 0.f ? e0 : 0.2f * e0;
    float e1 = v.y + xr_t.y; e1 = e1 >= 0.f ? e1 : 0.2f * e1;
    float p = e0 * a_t.x + e1 * a_t.y;
    p += __shfl_xor(p, 8);
    p += __shfl_xor(p, 4);
    p += __shfl_xor(p, 2);
    p += __shfl_xor(p, 1);
    return p;
}

__global__ __launch_bounds__(256) void gat_edge_kernel(
    const __half2* __restrict__ xlh, const float2* __restrict__ xr2,
    const int* __restrict__ srcs, const int* __restrict__ row_ptr,
    const float2* __restrict__ att2, const float2* __restrict__ bias2,
    float2* __restrict__ outf, __half2* __restrict__ outh,
    int N, int do_relu, int out_half)
{
    int node = blockIdx.x * 4 + threadIdx.y;
    int t = threadIdx.x;                       // 0..63
    if (node >= N) return;
    float2 xr_t = xr2[(size_t)node * 64 + t];
    float2 a_t  = att2[t];
    int beg = row_ptr[node], end = row_ptr[node + 1];
    float s = 0.f;
    float ox = 0.f, oy = 0.f;
    int i = beg;
    for (; i + 4 <= end; i += 4) {
        int sn0 = srcs[i], sn1 = srcs[i + 1], sn2 = srcs[i + 2], sn3 = srcs[i + 3];
        float2 v0 = __half22float2(xlh[(size_t)sn0 * 64 + t]);
        float2 v1 = __half22float2(xlh[(size_t)sn1 * 64 + t]);
        float2 v2 = __half22float2(xlh[(size_t)sn2 * 64 + t]);
        float2 v3 = __half22float2(xlh[(size_t)sn3 * 64 + t]);
        float p0 = edge_logit(v0, xr_t, a_t);
        float p1 = edge_logit(v1, xr_t, a_t);
        float p2 = edge_logit(v2, xr_t, a_t);
        float p3 = edge_logit(v3, xr_t, a_t);
        float w0 = __expf(p0), w1 = __expf(p1), w2 = __expf(p2), w3 = __expf(p3);
        s += (w0 + w1) + (w2 + w3);
        ox = fmaf(w0, v0.x, ox); oy = fmaf(w0, v0.y, oy);
        ox = fmaf(w1, v1.x, ox); oy = fmaf(w1, v1.y, oy);
        ox = fmaf(w2, v2.x, ox); oy = fmaf(w2, v2.y, oy);
        ox = fmaf(w3, v3.x, ox); oy = fmaf(w3, v3.y, oy);
    }
    for (; i < end; ++i) {
        int sn = srcs[i];
        float2 v = __half22float2(xlh[(size_t)sn * 64 + t]);
        float p = edge_logit(v, xr_t, a_t);
        float w = __expf(p);
        s += w;
        ox = fmaf(w, v.x, ox); oy = fmaf(w, v.y, oy);
    }
    float inv = 1.f / (s + 1e-16f);
    float2 bi = bias2[t];
    float rx = ox * inv + bi.x;
    float ry = oy * inv + bi.y;
    if (do_relu) { rx = fmaxf(rx, 0.f); ry = fmaxf(ry, 0.f); }
    if (out_half) {
        outh[(size_t)node * 64 + t] = __floats2half2_rn(rx, ry);
    } else {
        float2 rr; rr.x = rx; rr.y = ry;
        outf[(size_t)node * 64 + t] = rr;
    }
}

// ---------------- launch ----------------

extern "C" void kernel_launch(void* const* d_in, const int* in_sizes, int n_in,
                              void* d_out, int out_size, void* d_ws, size_t ws_size,
                              hipStream_t stream)
{
    const float* x    = (const float*)d_in[0];
    const int*   ei   = (const int*)d_in[1];
    const float* Wl1  = (const float*)d_in[2];
    const float* Wr1  = (const float*)d_in[3];
    const float* Wl2  = (const float*)d_in[4];
    const float* Wr2  = (const float*)d_in[5];
    const float* bl1  = (const float*)d_in[6];
    const float* br1  = (const float*)d_in[7];
    const float* bl2  = (const float*)d_in[8];
    const float* br2  = (const float*)d_in[9];
    const float* att1 = (const float*)d_in[10];
    const float* att2 = (const float*)d_in[11];
    const float* b1   = (const float*)d_in[12];
    const float* b2   = (const float*)d_in[13];

    const int N = in_sizes[0] / F;
    const int E = in_sizes[1] / 2;
    const int* src = ei;
    const int* dst = ei + E;

    char* ws = (char*)d_ws;
    size_t off = 0;
    auto alloc = [&](size_t bytes) -> void* {
        void* p = ws + off;
        off = (off + bytes + 255) & ~(size_t)255;
        return p;
    };
    _Float16* xh   = (_Float16*)alloc((size_t)N * F * sizeof(_Float16));  // fp16 input (layer1)
    _Float16* hh   = (_Float16*)alloc((size_t)N * F * sizeof(_Float16));  // fp16 h (layer2 in)
    _Float16* xlh  = (_Float16*)alloc((size_t)N * F * sizeof(_Float16));  // fp16 xl
    float*    xr   = (float*)alloc((size_t)N * F * sizeof(float));        // fp32 xr
    _Float16* Wt1l = (_Float16*)alloc((size_t)F * F * sizeof(_Float16));
    _Float16* Wt1r = (_Float16*)alloc((size_t)F * F * sizeof(_Float16));
    _Float16* Wt2l = (_Float16*)alloc((size_t)F * F * sizeof(_Float16));
    _Float16* Wt2r = (_Float16*)alloc((size_t)F * F * sizeof(_Float16));
    int* row_ptr   = (int*)alloc((size_t)(N + 1) * sizeof(int));
    int* deg       = (int*)alloc((size_t)N * sizeof(int));
    int* excl      = (int*)alloc((size_t)N * sizeof(int));
    int* bsums     = (int*)alloc((size_t)1024 * sizeof(int));
    int* cursor    = (int*)alloc((size_t)N * sizeof(int));
    int* srcs      = (int*)alloc((size_t)E * sizeof(int));

    // CSR build
    hipMemsetAsync(deg, 0, (size_t)N * sizeof(int), stream);
    count_deg_kernel<<<(E + 255) / 256, 256, 0, stream>>>(dst, deg, E);
    const int nchunks = (N + 1023) / 1024;
    scan1_kernel<<<nchunks, 1024, 0, stream>>>(deg, excl, bsums, N);
    scan2_kernel<<<1, 1024, 0, stream>>>(bsums, nchunks);
    scan3_kernel<<<(N + 256) / 256, 256, 0, stream>>>(excl, bsums, row_ptr, cursor, N, E);
    scatter_kernel<<<(E + 255) / 256, 256, 0, stream>>>(src, dst, cursor, srcs, E);

    // converts
    const int n8 = N * F / 8;
    convx_kernel<<<(n8 + 255) / 256, 256, 0, stream>>>((const float4*)x, (f16x8*)xh, n8);
    convw_kernel<<<256, 256, 0, stream>>>(Wl1, Wr1, Wl2, Wr2, Wt1l, Wt1r, Wt2l, Wt2r);

    const int gemm_blocks = (N + 63) / 64;
    dim3 eb(64, 4);
    const int edge_blocks = (N + 3) / 4;

    // layer 1
    mfma_dual_gemm_kernel<<<gemm_blocks, 256, 0, stream>>>(
        xh, Wt1l, bl1, Wt1r, br1, xlh, xr, N);
    gat_edge_kernel<<<edge_blocks, eb, 0, stream>>>(
        (const __half2*)xlh, (const float2*)xr, srcs, row_ptr,
        (const float2*)att1, (const float2*)b1,
        nullptr, (__half2*)hh, N, 1, 1);

    // layer 2
    mfma_dual_gemm_kernel<<<gemm_blocks, 256, 0, stream>>>(
        hh, Wt2l, bl2, Wt2r, br2, xlh, xr, N);
    gat_edge_kernel<<<edge_blocks, eb, 0, stream>>>(
        (const __half2*)xlh, (const float2*)xr, srcs, row_ptr,
        (const float2*)att2, (const float2*)b2,
        (float2*)d_out, nullptr, N, 0, 0);
}